// Round 1
// baseline (111.762 us; speedup 1.0000x reference)
//
#include <hip/hip_runtime.h>
#include <hip/hip_bf16.h>

typedef __attribute__((ext_vector_type(8))) __bf16 bf16x8;
typedef __attribute__((ext_vector_type(4))) float  f32x4;

constexpr int NROW = 8192;
constexpr int DDIM = 256;
constexpr int KDIM = 512;           // 2*DDIM, packed [x | e]
constexpr int BM = 128, BN = 128, BK = 32;

__device__ __forceinline__ void gload_lds16(const void* g, void* l) {
  __builtin_amdgcn_global_load_lds(
      (const __attribute__((address_space(1))) void*)g,
      (__attribute__((address_space(3))) void*)l, 16, 0, 0);
}

// ---------------- prep: pack P = [bf16(x) | bf16(exp(1-dc))], s_i = (1-p)/d * |x_i|^2
__global__ __launch_bounds__(256) void prep_kernel(
    const float* __restrict__ x, const float* __restrict__ dc,
    const float* __restrict__ pparm,
    __hip_bfloat16* __restrict__ P, float* __restrict__ s)
{
  const int row = blockIdx.x;
  const int t   = threadIdx.x;
  const float xv = x[(size_t)row * DDIM + t];
  const float ev = __expf(1.0f - dc[(size_t)row * DDIM + t]);
  P[(size_t)row * KDIM + t]        = __float2bfloat16(xv);
  P[(size_t)row * KDIM + DDIM + t] = __float2bfloat16(ev);

  float v = xv * xv;
  #pragma unroll
  for (int off = 32; off > 0; off >>= 1) v += __shfl_down(v, off, 64);
  __shared__ float red[4];
  const int lane = t & 63, wid = t >> 6;
  if (lane == 0) red[wid] = v;
  __syncthreads();
  if (t == 0) {
    const float p = pparm[0];
    s[row] = (1.0f - p) * (1.0f / (float)DDIM) * (red[0] + red[1] + red[2] + red[3]);
  }
}

// ---------------- GEMM: G = P @ P^T with segment scaling; sim = 1/(s_i+s_j+G), diag=1
__global__ __launch_bounds__(256) void adj_gemm(
    const __hip_bfloat16* __restrict__ P, const float* __restrict__ s,
    const float* __restrict__ pparm, float* __restrict__ out)
{
  __shared__ __align__(16) __hip_bfloat16 As[BM * BK];
  __shared__ __align__(16) __hip_bfloat16 Bs[BN * BK];

  const float p  = pparm[0];
  const float cx = -2.0f * (1.0f - p) / (float)DDIM;
  const float ce = p / (float)DDIM;
  const float midscale = cx / ce;          // applied after x-segment

  // XCD-aware swizzle: 4096 blocks, 8 XCDs, 512 blocks/XCD.
  // Within an XCD chunk: column-major over an 8-row band of tiles so the
  // XCD's A panel (1 MB) stays L2-resident while B tiles stream.
  const int orig  = blockIdx.x;
  const int xcd   = orig & 7;
  const int local = orig >> 3;             // 0..511
  const int bi = xcd * 8 + (local & 7);    // 0..63
  const int bj = local >> 3;               // 0..63
  const int rowBase = bi * BM;
  const int colBase = bj * BN;

  const int t    = threadIdx.x;
  const int lane = t & 63;
  const int wid  = t >> 6;                 // 4 waves, 2x2
  const int wr   = wid >> 1, wc = wid & 1;

  f32x4 acc[4][4];
  #pragma unroll
  for (int m = 0; m < 4; ++m)
    #pragma unroll
    for (int n = 0; n < 4; ++n)
      acc[m][n] = (f32x4){0.f, 0.f, 0.f, 0.f};

  const int frow = lane & 15;              // row/col within 16x16 fragment
  const int kq   = lane >> 4;              // k-quarter (0..3), 8 bf16 each

  // staging chunk ids (16B chunks, 4 per 32-elem row)
  const int q0 = wid * 64 + lane;          // 0..255
  const int q1 = q0 + 256;                 // 256..511

  for (int kt = 0; kt < KDIM / BK; ++kt) {
    const int k0 = kt * BK;
    __syncthreads();   // previous iter's LDS reads done before overwrite
    // ---- stage A tile (rows rowBase..+128, k0..k0+32) and B tile
    {
      const __hip_bfloat16* ga0 = P + (size_t)(rowBase + (q0 >> 2)) * KDIM + k0 + (q0 & 3) * 8;
      gload_lds16(ga0, As + wid * 512);
      const __hip_bfloat16* ga1 = P + (size_t)(rowBase + (q1 >> 2)) * KDIM + k0 + (q1 & 3) * 8;
      gload_lds16(ga1, As + 2048 + wid * 512);
      const __hip_bfloat16* gb0 = P + (size_t)(colBase + (q0 >> 2)) * KDIM + k0 + (q0 & 3) * 8;
      gload_lds16(gb0, Bs + wid * 512);
      const __hip_bfloat16* gb1 = P + (size_t)(colBase + (q1 >> 2)) * KDIM + k0 + (q1 & 3) * 8;
      gload_lds16(gb1, Bs + 2048 + wid * 512);
    }
    __syncthreads();   // compiler drains vmcnt before barrier

    bf16x8 a[4], b[4];
    #pragma unroll
    for (int m = 0; m < 4; ++m)
      a[m] = *(const bf16x8*)(As + (wr * 64 + m * 16 + frow) * BK + kq * 8);
    #pragma unroll
    for (int n = 0; n < 4; ++n)
      b[n] = *(const bf16x8*)(Bs + (wc * 64 + n * 16 + frow) * BK + kq * 8);

    #pragma unroll
    for (int m = 0; m < 4; ++m)
      #pragma unroll
      for (int n = 0; n < 4; ++n)
        acc[m][n] = __builtin_amdgcn_mfma_f32_16x16x32_bf16(a[m], b[n], acc[m][n], 0, 0, 0);

    // after the x-segment (k < 256): acc = Sx  ->  acc *= cx/ce
    if (kt == (DDIM / BK) - 1) {
      #pragma unroll
      for (int m = 0; m < 4; ++m)
        #pragma unroll
        for (int n = 0; n < 4; ++n)
          acc[m][n] *= midscale;
    }
  }

  // ---- epilogue: denom = s_i + s_j + ce*acc ; out = 1/denom (diag = 1)
  #pragma unroll
  for (int m = 0; m < 4; ++m) {
    const int growb = rowBase + wr * 64 + m * 16 + (lane >> 4) * 4;
    float srow[4];
    #pragma unroll
    for (int r = 0; r < 4; ++r) srow[r] = s[growb + r];
    #pragma unroll
    for (int n = 0; n < 4; ++n) {
      const int gcol = colBase + wc * 64 + n * 16 + (lane & 15);
      const float scol = s[gcol];
      #pragma unroll
      for (int r = 0; r < 4; ++r) {
        const int grow = growb + r;
        const float denom = srow[r] + scol + ce * acc[m][n][r];
        const float val = (grow == gcol) ? 1.0f : __builtin_amdgcn_rcpf(denom);
        out[(size_t)grow * NROW + gcol] = val;
      }
    }
  }
}

extern "C" void kernel_launch(void* const* d_in, const int* in_sizes, int n_in,
                              void* d_out, int out_size, void* d_ws, size_t ws_size,
                              hipStream_t stream) {
  const float* x  = (const float*)d_in[0];
  const float* dc = (const float*)d_in[1];
  const float* pp = (const float*)d_in[2];
  float* out = (float*)d_out;

  __hip_bfloat16* P = (__hip_bfloat16*)d_ws;                       // 8192*512*2 = 8 MB
  float* s = (float*)((char*)d_ws + (size_t)NROW * KDIM * 2);      // + 32 KB

  prep_kernel<<<NROW, 256, 0, stream>>>(x, dc, pp, P, s);
  adj_gemm<<<(NROW / BM) * (NROW / BN), 256, 0, stream>>>(P, s, pp, out);
}

// Round 2
// 106.432 us; speedup vs baseline: 1.0501x; 1.0501x over previous
//
#include <hip/hip_runtime.h>
#include <hip/hip_bf16.h>

typedef __attribute__((ext_vector_type(8))) __bf16 bf16x8;
typedef __attribute__((ext_vector_type(4))) float  f32x4;

constexpr int NROW = 8192;
constexpr int DDIM = 256;
constexpr int KDIM = 512;               // packed [x | e]
constexpr int BM = 256, BN = 128, BK = 64;
constexpr int NT = KDIM / BK;           // 8 K-tiles
constexpr int ABYTES = BM * BK * 2;     // 32 KB
constexpr int BBYTES = BN * BK * 2;     // 16 KB
constexpr int BUFBYTES = ABYTES + BBYTES; // 48 KB
constexpr int NBUF = 3;                 // depth-2 prefetch, no WAR hazard
constexpr int LDS_TOTAL = NBUF * BUFBYTES; // 144 KB

__device__ __forceinline__ void gload_lds16(const void* g, void* l) {
  __builtin_amdgcn_global_load_lds(
      (const __attribute__((address_space(1))) void*)g,
      (__attribute__((address_space(3))) void*)l, 16, 0, 0);
}

// ---------------- prep: P = [bf16(x) | bf16(exp(1-dc))], s_i = (1-p)/d*|x_i|^2
__global__ __launch_bounds__(256) void prep_kernel(
    const float* __restrict__ x, const float* __restrict__ dc,
    const float* __restrict__ pparm,
    __hip_bfloat16* __restrict__ P, float* __restrict__ s)
{
  const int row = blockIdx.x;
  const int t   = threadIdx.x;
  const float xv = x[(size_t)row * DDIM + t];
  const float ev = __expf(1.0f - dc[(size_t)row * DDIM + t]);
  P[(size_t)row * KDIM + t]        = __float2bfloat16(xv);
  P[(size_t)row * KDIM + DDIM + t] = __float2bfloat16(ev);

  float v = xv * xv;
  #pragma unroll
  for (int off = 32; off > 0; off >>= 1) v += __shfl_down(v, off, 64);
  __shared__ float red[4];
  const int lane = t & 63, wid = t >> 6;
  if (lane == 0) red[wid] = v;
  __syncthreads();
  if (t == 0) {
    const float p = pparm[0];
    s[row] = (1.0f - p) * (1.0f / (float)DDIM) * (red[0] + red[1] + red[2] + red[3]);
  }
}

// ---------------- GEMM: G = P @ P^T segment-scaled; sim = 1/(s_i+s_j+ce*G), diag=1
__global__ void __launch_bounds__(512, 2) adj_gemm(
    const __hip_bfloat16* __restrict__ P, const float* __restrict__ s,
    const float* __restrict__ pparm, float* __restrict__ out)
{
  extern __shared__ char lds[];

  const float p  = pparm[0];
  const float cx = -2.0f * (1.0f - p) / (float)DDIM;
  const float ce = p / (float)DDIM;
  const float midscale = cx / ce;

  // XCD-aware: 2048 blocks; XCD x owns row-tile band [x*4, x*4+4) x all 64 col-tiles
  const int orig  = blockIdx.x;
  const int x     = orig & 7;
  const int local = orig >> 3;             // 0..255
  const int bi = x * 4 + (local & 3);      // 0..31
  const int bj = local >> 2;               // 0..63
  const int rowBase = bi * BM;
  const int colBase = bj * BN;

  const int tid  = threadIdx.x;
  const int lane = tid & 63;
  const int wid  = tid >> 6;               // 8 waves, 4(M) x 2(N)
  const int wrow = (wid >> 1) * 64;
  const int wcol = (wid & 1) * 64;
  const int frow = lane & 15;
  const int kq   = lane >> 4;

  // ---- staging precompute: linear LDS dest (o), pre-swizzled global source.
  // swizzle: byte ^= ((byte>>9)&1)<<5  (row bit2 XOR into 32B-granule bit)
  const char* Pc = (const char*)P;
  const char* gsrc[6];
  int ldst[6];
  #pragma unroll
  for (int j = 0; j < 4; ++j) {            // A region: 256x64 bf16 = 32 KB
    const int o  = (j * 512 + tid) * 16;
    const int r  = o >> 7;
    const int cb = (o & 127) ^ (((o >> 9) & 1) << 5);
    gsrc[j] = Pc + ((size_t)(rowBase + r) * KDIM) * 2 + cb;
    ldst[j] = o;
  }
  #pragma unroll
  for (int j = 0; j < 2; ++j) {            // B region: 128x64 bf16 = 16 KB
    const int o  = (j * 512 + tid) * 16;
    const int r  = o >> 7;
    const int cb = (o & 127) ^ (((o >> 9) & 1) << 5);
    gsrc[4 + j] = Pc + ((size_t)(colBase + r) * KDIM) * 2 + cb;
    ldst[4 + j] = ABYTES + o;
  }

  // ---- prologue: stage tile 0 -> buf0, tile 1 -> buf1 (12 loads in flight)
  #pragma unroll
  for (int j = 0; j < 6; ++j) gload_lds16(gsrc[j],       lds + ldst[j]);
  #pragma unroll
  for (int j = 0; j < 6; ++j) gload_lds16(gsrc[j] + 128, lds + BUFBYTES + ldst[j]);

  f32x4 acc[4][4];
  #pragma unroll
  for (int m = 0; m < 4; ++m)
    #pragma unroll
    for (int n = 0; n < 4; ++n)
      acc[m][n] = (f32x4){0.f, 0.f, 0.f, 0.f};

  #pragma unroll
  for (int t = 0; t < NT; ++t) {
    // tile-t boundary: wait tile t landed (newest 6 = tile t+1 stay in flight)
    if (t < NT - 1) asm volatile("s_waitcnt vmcnt(6)" ::: "memory");
    else            asm volatile("s_waitcnt vmcnt(0)" ::: "memory");
    asm volatile("s_barrier" ::: "memory");

    char* buf  = lds + (t % NBUF) * BUFBYTES;
    char* nbuf = lds + ((t + 2) % NBUF) * BUFBYTES;
    const int gadv = (t + 2) * (BK * 2);

    // ---- phase 0: read A frags + B frags n0-1, issue 3 prefetch loads, MFMA
    bf16x8 a[4][2], bb[4][2];
    #pragma unroll
    for (int m = 0; m < 4; ++m)
      #pragma unroll
      for (int ks = 0; ks < 2; ++ks) {
        const int row = wrow + m * 16 + frow;
        const int cb  = (ks * 64 + kq * 16) ^ (((row >> 2) & 1) << 5);
        a[m][ks] = *(const bf16x8*)(buf + row * 128 + cb);
      }
    #pragma unroll
    for (int n = 0; n < 2; ++n)
      #pragma unroll
      for (int ks = 0; ks < 2; ++ks) {
        const int row = wcol + n * 16 + frow;
        const int cb  = (ks * 64 + kq * 16) ^ (((row >> 2) & 1) << 5);
        bb[n][ks] = *(const bf16x8*)(buf + ABYTES + row * 128 + cb);
      }
    if (t + 2 < NT) {
      gload_lds16(gsrc[0] + gadv, nbuf + ldst[0]);
      gload_lds16(gsrc[1] + gadv, nbuf + ldst[1]);
      gload_lds16(gsrc[2] + gadv, nbuf + ldst[2]);
    }
    __builtin_amdgcn_s_setprio(1);
    #pragma unroll
    for (int m = 0; m < 4; ++m)
      #pragma unroll
      for (int n = 0; n < 2; ++n)
        #pragma unroll
        for (int ks = 0; ks < 2; ++ks)
          acc[m][n] = __builtin_amdgcn_mfma_f32_16x16x32_bf16(a[m][ks], bb[n][ks], acc[m][n], 0, 0, 0);
    __builtin_amdgcn_s_setprio(0);
    asm volatile("s_barrier" ::: "memory");

    // ---- phase 1: read B frags n2-3, issue 3 prefetch loads, MFMA
    #pragma unroll
    for (int n = 2; n < 4; ++n)
      #pragma unroll
      for (int ks = 0; ks < 2; ++ks) {
        const int row = wcol + n * 16 + frow;
        const int cb  = (ks * 64 + kq * 16) ^ (((row >> 2) & 1) << 5);
        bb[n][ks] = *(const bf16x8*)(buf + ABYTES + row * 128 + cb);
      }
    if (t + 2 < NT) {
      gload_lds16(gsrc[3] + gadv, nbuf + ldst[3]);
      gload_lds16(gsrc[4] + gadv, nbuf + ldst[4]);
      gload_lds16(gsrc[5] + gadv, nbuf + ldst[5]);
    }
    __builtin_amdgcn_s_setprio(1);
    #pragma unroll
    for (int m = 0; m < 4; ++m)
      #pragma unroll
      for (int n = 2; n < 4; ++n)
        #pragma unroll
        for (int ks = 0; ks < 2; ++ks)
          acc[m][n] = __builtin_amdgcn_mfma_f32_16x16x32_bf16(a[m][ks], bb[n][ks], acc[m][n], 0, 0, 0);
    __builtin_amdgcn_s_setprio(0);

    // after x-segment (k<256): acc = Sx -> scale by cx/ce
    if (t == DDIM / BK - 1) {
      #pragma unroll
      for (int m = 0; m < 4; ++m)
        #pragma unroll
        for (int n = 0; n < 4; ++n)
          acc[m][n] *= midscale;
    }
  }

  // ---- epilogue: denom = s_i + s_j + ce*acc ; out = 1/denom (diag = 1)
  #pragma unroll
  for (int m = 0; m < 4; ++m) {
    const int growb = rowBase + wrow + m * 16 + (lane >> 4) * 4;
    float srow[4];
    #pragma unroll
    for (int r = 0; r < 4; ++r) srow[r] = s[growb + r];
    #pragma unroll
    for (int n = 0; n < 4; ++n) {
      const int gcol = colBase + wcol + n * 16 + (lane & 15);
      const float scol = s[gcol];
      #pragma unroll
      for (int r = 0; r < 4; ++r) {
        const int grow = growb + r;
        const float denom = srow[r] + scol + ce * acc[m][n][r];
        const float val = (grow == gcol) ? 1.0f : __builtin_amdgcn_rcpf(denom);
        out[(size_t)grow * NROW + gcol] = val;
      }
    }
  }
}

extern "C" void kernel_launch(void* const* d_in, const int* in_sizes, int n_in,
                              void* d_out, int out_size, void* d_ws, size_t ws_size,
                              hipStream_t stream) {
  const float* x  = (const float*)d_in[0];
  const float* dc = (const float*)d_in[1];
  const float* pp = (const float*)d_in[2];
  float* out = (float*)d_out;

  __hip_bfloat16* P = (__hip_bfloat16*)d_ws;                       // 8 MB
  float* s = (float*)((char*)d_ws + (size_t)NROW * KDIM * 2);      // +32 KB

  hipFuncSetAttribute(reinterpret_cast<const void*>(adj_gemm),
                      hipFuncAttributeMaxDynamicSharedMemorySize, LDS_TOTAL);

  prep_kernel<<<NROW, 256, 0, stream>>>(x, dc, pp, P, s);
  adj_gemm<<<(NROW / BM) * (NROW / BN), 512, LDS_TOTAL, stream>>>(P, s, pp, out);
}